// Round 3
// baseline (243.126 us; speedup 1.0000x reference)
//
#include <hip/hip_runtime.h>

// VQ: x (16,64,64,64) f32, codebook e_i_ts (64,1024) f32.
// N = 65536 positions, D = 64, K = 1024.
//
// The harness reference ("ref=np") evaluates
//   d[p][k] = fl32( fl32( A_p - 2*B_pk ) + C_k )
// in numpy float32, where A = sum(x^2) (pairwise-8), B = sgemm (sequential-k
// single-accumulator FMA), C = sum(e^2, axis=0) (sequential-d). Distances sit
// near ||x||^2 ~ 60, so fp32 quantizes scores to a ~4e-6 grid; argmin at
// near-ties follows THAT grid. We emulate the arithmetic bit-exactly so the
// argmin (first-index tie-break, like np.argmin) matches at every position.

#define D 64
#define K 1024
#define NPOS 65536
#define HW 4096  // 64*64 spatial per batch

// ---- prep: transpose codebook (D,K) -> eT (K,D); c2[k] = np.sum(e**2, 0) ----
// numpy axis-0 reduce: out = sq[0]; out += sq[d] for d=1..63 (sequential),
// squares pre-rounded to fp32. __fmul_rn blocks FMA contraction.
__global__ void vq_prep_kernel(const float* __restrict__ e,
                               float* __restrict__ eT,
                               float* __restrict__ c2) {
    int k = blockIdx.x * blockDim.x + threadIdx.x;
    if (k >= K) return;
    float s = 0.f;
#pragma unroll
    for (int d = 0; d < D; ++d) {
        float v = e[d * K + k];          // lanes read consecutive k: coalesced
        eT[k * D + d] = v;
        float sq = __fmul_rn(v, v);      // rounded square, no contraction
        s = s + sq;                      // sequential adds (0 + sq0 is exact)
    }
    c2[k] = s;
}

// ---- main: one lane per position; 4 waves split K into 4x256 ----
__global__ __launch_bounds__(256, 4)
void vq_main_kernel(const float* __restrict__ x,
                    const float* __restrict__ eT,
                    const float* __restrict__ c2,
                    float* __restrict__ out) {
    __shared__ float sS[4][64];
    __shared__ int   sKk[4][64];
    __shared__ int   sBest[64];

    const int lane = threadIdx.x & 63;
    const int w    = threadIdx.x >> 6;
    const int p    = blockIdx.x * 64 + lane;       // position index
    const int b    = p >> 12;                      // batch
    const int sp   = p & (HW - 1);                 // spatial offset (h*64+w)

    const float* xp = x + (size_t)b * D * HW + sp;
    float xv[D];
#pragma unroll
    for (int d = 0; d < D; ++d) xv[d] = xp[(size_t)d * HW];  // coalesced per d

    // A_p = np.sum(flat_x**2, axis=1): numpy pairwise_sum, n=64 -> the
    // 8-accumulator unrolled block, squares rounded first.
    float r[8];
#pragma unroll
    for (int i = 0; i < 8; ++i) r[i] = __fmul_rn(xv[i], xv[i]);
#pragma unroll
    for (int j = 1; j < 8; ++j)
#pragma unroll
        for (int i = 0; i < 8; ++i) {
            float sq = __fmul_rn(xv[8 * j + i], xv[8 * j + i]);
            r[i] = r[i] + sq;
        }
    const float A = ((r[0] + r[1]) + (r[2] + r[3]))
                  + ((r[4] + r[5]) + (r[6] + r[7]));

    // wave-uniform k-base so codebook/c2 loads scalarize (s_load)
    const int kbase = __builtin_amdgcn_readfirstlane(w * 256);

    float s1 = 3.4e38f;
    int   k1 = kbase;
    for (int kk = 0; kk < 256; kk += 2) {          // 2 codes/iter for ILP
        const int ka = kbase + kk;
        const int kb = ka + 1;
        const float* __restrict__ ea = eT + (size_t)ka * D;
        const float* __restrict__ ebr = ea + D;
        // B_pk: OpenBLAS sgemm = sequential-k single-accumulator FMA chain
        float ba = 0.f, bb = 0.f;
#pragma unroll
        for (int d = 0; d < D; ++d) {
            ba = __builtin_fmaf(xv[d], ea[d], ba);
            bb = __builtin_fmaf(xv[d], ebr[d], bb);
        }
        // fl(A - 2B): fmaf(-2,B,A) == np's A - (2.0f*B) (x2 exact, 1 rounding)
        // then + C_k: second rounding. Matches np elementwise chain.
        const float sa = __builtin_fmaf(-2.f, ba, A) + c2[ka];
        const float sb = __builtin_fmaf(-2.f, bb, A) + c2[kb];
        if (sa < s1) { s1 = sa; k1 = ka; }         // strict <, ascending k:
        if (sb < s1) { s1 = sb; k1 = kb; }         //   np.argmin first-index
    }

    sS[w][lane]  = s1;
    sKk[w][lane] = k1;
    __syncthreads();

    if (w == 0) {
        float bs = sS[0][lane];
        int   bk = sKk[0][lane];
#pragma unroll
        for (int j = 1; j < 4; ++j) {
            const float s  = sS[j][lane];
            const int   k2 = sKk[j][lane];
            if (s < bs || (s == bs && k2 < bk)) { bs = s; bk = k2; }
        }
        sBest[lane] = bk;
    }
    __syncthreads();

    const int bk = sBest[lane];
    const float* __restrict__ ebest = eT + (size_t)bk * D;
    float* op = out + (size_t)b * D * HW + sp;
#pragma unroll
    for (int j = 0; j < 16; ++j) {
        const int c  = w * 16 + j;                 // 4 waves split 64 channels
        const float xq = xp[(size_t)c * HW];       // this lane's position
        const float q  = ebest[c];
        op[(size_t)c * HW] = xq + (q - xq);        // np STE: fl(x + fl(q-x))
    }
}

extern "C" void kernel_launch(void* const* d_in, const int* in_sizes, int n_in,
                              void* d_out, int out_size, void* d_ws, size_t ws_size,
                              hipStream_t stream) {
    const float* x = (const float*)d_in[0];
    const float* e = (const float*)d_in[1];
    float* out = (float*)d_out;

    float* eT = (float*)d_ws;                    // K*D floats = 256 KB
    float* c2 = eT + (size_t)K * D;              // K floats

    vq_prep_kernel<<<K / 256, 256, 0, stream>>>(e, eT, c2);
    vq_main_kernel<<<NPOS / 64, 256, 0, stream>>>(x, eT, c2, out);
}

// Round 4
// 234.098 us; speedup vs baseline: 1.0386x; 1.0386x over previous
//
#include <hip/hip_runtime.h>

// VQ: x (16,64,64,64) f32, codebook e_i_ts (64,1024) f32.
// N = 65536 positions, D = 64, K = 1024.
//
// Bit-exact emulation of the harness's numpy-fp32 reference:
//   d[p][k] = fl32( fl32( A_p - 2*B_pk ) + C_k )
// A = np pairwise-8 sum of squares; B = sgemm sequential-k FMA chain;
// C = sequential axis-0 sum of rounded squares. Argmin ties: first index.
//
// R4: __launch_bounds__(256,2) raises VGPR budget 128->256 so xv[64] stays in
// architectural VGPRs (R3's (256,4) forced AGPR spill: VGPR_Count=40, every
// xv use paid a v_accvgpr_read -> 2x VALU issue, 188us). 4 codes/iter gives
// 4 indep FMA chains/wave to saturate VALU at 2 waves/SIMD.

#define D 64
#define K 1024
#define NPOS 65536
#define HW 4096  // 64*64 spatial per batch

// ---- prep: transpose codebook (D,K) -> eT (K,D); c2[k] = np.sum(e**2, 0) ----
__global__ void vq_prep_kernel(const float* __restrict__ e,
                               float* __restrict__ eT,
                               float* __restrict__ c2) {
    int k = blockIdx.x * blockDim.x + threadIdx.x;
    if (k >= K) return;
    float s = 0.f;
#pragma unroll
    for (int d = 0; d < D; ++d) {
        float v = e[d * K + k];          // lanes read consecutive k: coalesced
        eT[k * D + d] = v;
        float sq = __fmul_rn(v, v);      // rounded square, no contraction
        s = s + sq;                      // sequential adds
    }
    c2[k] = s;
}

// ---- main: one lane per position; 4 waves split K into 4x256 ----
__global__ __launch_bounds__(256, 2)
void vq_main_kernel(const float* __restrict__ x,
                    const float* __restrict__ eT,
                    const float* __restrict__ c2,
                    float* __restrict__ out) {
    __shared__ float sS[4][64];
    __shared__ int   sKk[4][64];
    __shared__ int   sBest[64];

    const int lane = threadIdx.x & 63;
    const int w    = threadIdx.x >> 6;
    const int p    = blockIdx.x * 64 + lane;       // position index
    const int b    = p >> 12;                      // batch
    const int sp   = p & (HW - 1);                 // spatial offset (h*64+w)

    const float* xp = x + (size_t)b * D * HW + sp;
    float xv[D];
#pragma unroll
    for (int d = 0; d < D; ++d) xv[d] = xp[(size_t)d * HW];  // coalesced per d

    // A_p = np.sum(flat_x**2, axis=1): numpy pairwise_sum n=64 ->
    // 8-accumulator unrolled block, squares rounded first.
    float r[8];
#pragma unroll
    for (int i = 0; i < 8; ++i) r[i] = __fmul_rn(xv[i], xv[i]);
#pragma unroll
    for (int j = 1; j < 8; ++j)
#pragma unroll
        for (int i = 0; i < 8; ++i) {
            float sq = __fmul_rn(xv[8 * j + i], xv[8 * j + i]);
            r[i] = r[i] + sq;
        }
    const float A = ((r[0] + r[1]) + (r[2] + r[3]))
                  + ((r[4] + r[5]) + (r[6] + r[7]));

    // wave-uniform k-base so codebook/c2 loads scalarize (s_load)
    const int kbase = __builtin_amdgcn_readfirstlane(w * 256);

    float s1 = 3.4e38f;
    int   k1 = kbase;
    for (int kk = 0; kk < 256; kk += 4) {          // 4 codes/iter: 4 FMA chains
        const int k0 = kbase + kk;
        const float* __restrict__ e0 = eT + (size_t)k0 * D;
        float b0 = 0.f, b1 = 0.f, b2 = 0.f, b3 = 0.f;
#pragma unroll
        for (int d = 0; d < D; ++d) {
            const float xd = xv[d];
            b0 = __builtin_fmaf(xd, e0[d],         b0);   // sequential per-code
            b1 = __builtin_fmaf(xd, e0[D + d],     b1);   //   chains (sgemm
            b2 = __builtin_fmaf(xd, e0[2 * D + d], b2);   //   bit-exact order)
            b3 = __builtin_fmaf(xd, e0[3 * D + d], b3);
        }
        const float s0 = __builtin_fmaf(-2.f, b0, A) + c2[k0];
        const float sA = __builtin_fmaf(-2.f, b1, A) + c2[k0 + 1];
        const float sB = __builtin_fmaf(-2.f, b2, A) + c2[k0 + 2];
        const float sC = __builtin_fmaf(-2.f, b3, A) + c2[k0 + 3];
        if (s0 < s1) { s1 = s0; k1 = k0; }         // strict <, ascending k:
        if (sA < s1) { s1 = sA; k1 = k0 + 1; }     //   np.argmin first-index
        if (sB < s1) { s1 = sB; k1 = k0 + 2; }
        if (sC < s1) { s1 = sC; k1 = k0 + 3; }
    }

    sS[w][lane]  = s1;
    sKk[w][lane] = k1;
    __syncthreads();

    if (w == 0) {
        float bs = sS[0][lane];
        int   bk = sKk[0][lane];
#pragma unroll
        for (int j = 1; j < 4; ++j) {
            const float s  = sS[j][lane];
            const int   k2 = sKk[j][lane];
            if (s < bs || (s == bs && k2 < bk)) { bs = s; bk = k2; }
        }
        sBest[lane] = bk;
    }
    __syncthreads();

    const int bk = sBest[lane];
    const float* __restrict__ ebest = eT + (size_t)bk * D;
    float* op = out + (size_t)b * D * HW + sp;
#pragma unroll
    for (int j = 0; j < 16; ++j) {
        const int c  = w * 16 + j;                 // 4 waves split 64 channels
        const float xq = xp[(size_t)c * HW];
        const float q  = ebest[c];
        op[(size_t)c * HW] = xq + (q - xq);        // np STE: fl(x + fl(q-x))
    }
}

extern "C" void kernel_launch(void* const* d_in, const int* in_sizes, int n_in,
                              void* d_out, int out_size, void* d_ws, size_t ws_size,
                              hipStream_t stream) {
    const float* x = (const float*)d_in[0];
    const float* e = (const float*)d_in[1];
    float* out = (float*)d_out;

    float* eT = (float*)d_ws;                    // K*D floats = 256 KB
    float* c2 = eT + (size_t)K * D;              // K floats

    vq_prep_kernel<<<K / 256, 256, 0, stream>>>(e, eT, c2);
    vq_main_kernel<<<NPOS / 64, 256, 0, stream>>>(x, eT, c2, out);
}

// Round 5
// 226.333 us; speedup vs baseline: 1.0742x; 1.0343x over previous
//
#include <hip/hip_runtime.h>

// VQ: x (16,64,64,64) f32, codebook e_i_ts (64,1024) f32.
// N = 65536 positions, D = 64, K = 1024.
//
// Bit-exact emulation of the harness's numpy-fp32 reference (passed R3/R4,
// absmax 0): d[p][k] = fl32( fl32( A_p - 2*B_pk ) + C_k ), A = np pairwise-8
// sum of squares, B = sequential-d single-accumulator FMA chain, C =
// sequential axis-0 sum of rounded squares. Argmin ties: first index.
//
// R5: x-tile lives in LDS, not registers. R3/R4 showed the compiler AGPR-
// caches xv[64] regardless of launch bounds (VGPR_Count 40/44) and the hot
// loop pays ~2x VALU issue (125us busy vs 55us useful). Now: x via
// ds_read_b128 (LDS pipe), e via wave-uniform s_load (SMEM pipe), VGPRs hold
// only 8 accumulators + argmin state. An opaque-zero asm index per kk-iter
// stops LICM from hoisting the LDS reads back into registers.

#define D 64
#define K 1024
#define NPOS 65536
#define HW 4096  // 64*64 spatial per batch

typedef float vfloat4 __attribute__((ext_vector_type(4)));

// ---- prep: transpose codebook (D,K) -> eT (K,D); c2[k] = np.sum(e**2, 0) ----
__global__ void vq_prep_kernel(const float* __restrict__ e,
                               float* __restrict__ eT,
                               float* __restrict__ c2) {
    int k = blockIdx.x * blockDim.x + threadIdx.x;
    if (k >= K) return;
    float s = 0.f;
#pragma unroll
    for (int d = 0; d < D; ++d) {
        float v = e[d * K + k];          // lanes read consecutive k: coalesced
        eT[k * D + d] = v;
        float sq = __fmul_rn(v, v);      // rounded square, no contraction
        s = s + sq;                      // sequential adds
    }
    c2[k] = s;
}

// ---- main: one lane per position; 4 waves split K into 4x256 ----
__global__ __launch_bounds__(256, 4)
void vq_main_kernel(const float* __restrict__ x,
                    const float* __restrict__ eT,
                    const float* __restrict__ c2,
                    float* __restrict__ out) {
    __shared__ vfloat4 xs4[D / 4][64];   // x tile [d/4][pos], 16 KB
    __shared__ float sS[4][64];
    __shared__ int   sKk[4][64];
    __shared__ int   sBest[64];

    const int lane = threadIdx.x & 63;
    const int w    = threadIdx.x >> 6;
    const int bb   = (blockIdx.x * 64) >> 12;      // batch (block-uniform)
    const int sp0  = (blockIdx.x * 64) & (HW - 1); // spatial base (uniform)

    float* xsf = (float*)xs4;

    // ---- stage x tile: wave w loads d-rows [w*16, w*16+16), lane = position
    {
        const float* xb = x + (size_t)bb * D * HW + sp0;
#pragma unroll
        for (int j = 0; j < 16; ++j) {
            const int d = w * 16 + j;
            const float v = xb[(size_t)d * HW + lane];          // coalesced
            xsf[((d >> 2) * 64 + lane) * 4 + (d & 3)] = v;
        }
    }
    __syncthreads();

    // ---- A_p = np.sum(x**2, axis=1): pairwise-8, squares rounded first
    float A;
    {
        float r[8];
#pragma unroll
        for (int i = 0; i < 8; ++i) {
            const float v = xsf[((i >> 2) * 64 + lane) * 4 + (i & 3)];
            r[i] = __fmul_rn(v, v);
        }
#pragma unroll
        for (int j = 1; j < 8; ++j)
#pragma unroll
            for (int i = 0; i < 8; ++i) {
                const int dd = 8 * j + i;
                const float v = xsf[((dd >> 2) * 64 + lane) * 4 + (dd & 3)];
                r[i] = r[i] + __fmul_rn(v, v);
            }
        A = ((r[0] + r[1]) + (r[2] + r[3])) + ((r[4] + r[5]) + (r[6] + r[7]));
    }

    const int kbase = __builtin_amdgcn_readfirstlane(w * 256);
    const vfloat4* xcol = &xs4[0][lane];           // xcol[g*64] = d-chunk g

    float s1 = 3.4e38f;
    int   k1 = kbase;
    for (int kk = 0; kk < 256; kk += 8) {          // 8 codes/iter
        const int k0 = kbase + kk;
        const float* __restrict__ e0 = eT + (size_t)k0 * D;

        int gz = 0;
        asm volatile("" : "+v"(gz));   // opaque 0: x-reads not provably
                                       // loop-invariant -> no LICM/CSE to regs
        float bacc[8];
#pragma unroll
        for (int i = 0; i < 8; ++i) bacc[i] = 0.f;
#pragma unroll
        for (int g = 0; g < 16; ++g) {
            const vfloat4 x4 = xcol[gz + g * 64];  // ds_read_b128, lane-contig
#pragma unroll
            for (int j = 0; j < 4; ++j) {
                const int d = g * 4 + j;           // strictly ascending d:
                const float xd = x4[j];            //   sgemm bit-exact chain
#pragma unroll
                for (int i = 0; i < 8; ++i)
                    bacc[i] = __builtin_fmaf(xd, e0[i * D + d], bacc[i]);
            }
        }
#pragma unroll
        for (int i = 0; i < 8; ++i) {              // ascending i, strict <:
            const float si = __builtin_fmaf(-2.f, bacc[i], A) + c2[k0 + i];
            if (si < s1) { s1 = si; k1 = k0 + i; } //   np first-index argmin
        }
    }

    sS[w][lane]  = s1;
    sKk[w][lane] = k1;
    __syncthreads();

    if (w == 0) {
        float bs = sS[0][lane];
        int   bk = sKk[0][lane];
#pragma unroll
        for (int j = 1; j < 4; ++j) {
            const float s  = sS[j][lane];
            const int   k2 = sKk[j][lane];
            if (s < bs || (s == bs && k2 < bk)) { bs = s; bk = k2; }
        }
        sBest[lane] = bk;
    }
    __syncthreads();

    const int bk = sBest[lane];
    const float* __restrict__ ebest = eT + (size_t)bk * D;
    float* op = out + (size_t)bb * D * HW + sp0 + lane;
#pragma unroll
    for (int j = 0; j < 16; ++j) {
        const int c  = w * 16 + j;                 // 4 waves split 64 channels
        const float xq = xsf[((c >> 2) * 64 + lane) * 4 + (c & 3)];
        const float q  = ebest[c];
        op[(size_t)c * HW] = xq + (q - xq);        // np STE: fl(x + fl(q-x))
    }
}

extern "C" void kernel_launch(void* const* d_in, const int* in_sizes, int n_in,
                              void* d_out, int out_size, void* d_ws, size_t ws_size,
                              hipStream_t stream) {
    const float* x = (const float*)d_in[0];
    const float* e = (const float*)d_in[1];
    float* out = (float*)d_out;

    float* eT = (float*)d_ws;                    // K*D floats = 256 KB
    float* c2 = eT + (size_t)K * D;              // K floats

    vq_prep_kernel<<<K / 256, 256, 0, stream>>>(e, eT, c2);
    vq_main_kernel<<<NPOS / 64, 256, 0, stream>>>(x, eT, c2, out);
}

// Round 6
// 132.879 us; speedup vs baseline: 1.8297x; 1.7033x over previous
//
#include <hip/hip_runtime.h>

// VQ: x (16,64,64,64) f32, codebook e (64,1024) f32. N=65536, D=64, K=1024.
//
// R6: MFMA candidate generation + certified exact resolve.
//  - scores approximated via split-bf16 MFMA: x=xh+xl, e=eh+el (RNE, exact
//    residuals), B ~= xh*eh + xl*eh + xh*el. |approx - np_fp32| <= MARGIN/2
//    (worst-case split omission + fp32 accumulation bounds).
//  - per position track top-2; if s2-s1 > MARGIN, np argmin == k1 provably.
//  - else position goes to a worklist; fallback kernel redoes the R3-verified
//    bit-exact numpy-fp32 scan (sequential-k FMA chain, pairwise-8 A,
//    sequential C) and overwrites. Main writes every output; fallback
//    overwrites the ambiguous ones (stream-ordered).

#define D 64
#define K 1024
#define NPOS 65536
#define HW 4096
#define XSTRIDE 262144  // D*HW
#define MARGIN 1.0e-3f

typedef float vfloat4 __attribute__((ext_vector_type(4)));
typedef short short8  __attribute__((ext_vector_type(8)));

static __device__ __forceinline__ unsigned short bf16_rne(float f) {
    unsigned u = __float_as_uint(f);
    u += 0x7FFFu + ((u >> 16) & 1u);
    return (unsigned short)(u >> 16);
}
static __device__ __forceinline__ float bf16_to_f32(unsigned short h) {
    return __uint_as_float(((unsigned)h) << 16);
}

// ---- prep 1: codebook -> bf16 split B-fragments --------------------------
// frag layout: ebf[tile][s][split][lane][j], lane=q*16+n, value =
// split(e[d][k]), d=s*32+q*8+j, k=tile*16+n. Lane l reads 16B at l*16: the
// main kernel's B-frag load is perfectly coalesced.
__global__ void vq_prep_e(const float* __restrict__ e,
                          unsigned short* __restrict__ ebf) {
    const int tile = blockIdx.x;               // 0..63
    const int t = threadIdx.x;
    const int n = t & 15;
    const int dg = t >> 4;                     // 0..15
#pragma unroll
    for (int i = 0; i < 4; ++i) {
        const int d = dg * 4 + i;
        const float v = e[d * K + tile * 16 + n];
        const unsigned short hh = bf16_rne(v);
        const float rem = v - bf16_to_f32(hh);     // exact (Sterbenz)
        const unsigned short hl = bf16_rne(rem);
        const int s = d >> 5, q = (d >> 3) & 3, j = d & 7;
        const int lanei = q * 16 + n;
        ebf[(((tile * 2 + s) * 2 + 0) * 64 + lanei) * 8 + j] = hh;
        ebf[(((tile * 2 + s) * 2 + 1) * 64 + lanei) * 8 + j] = hl;
    }
}

// ---- prep 2: c2[k] = np.sum(e**2, axis=0) (sequential d, rounded squares);
// also zero the fallback worklist counter (ws is re-poisoned every launch).
__global__ void vq_prep_c2(const float* __restrict__ e,
                           float* __restrict__ c2,
                           int* __restrict__ wl_count) {
    if (blockIdx.x == 0 && threadIdx.x == 0) *wl_count = 0;
    const int k = blockIdx.x * 256 + threadIdx.x;
    float s = 0.f;
#pragma unroll
    for (int d = 0; d < D; ++d) {
        const float v = e[d * K + k];          // coalesced across lanes
        s = s + __fmul_rn(v, v);
    }
    c2[k] = s;
}

// ---- prep 3: A[p] = np.sum(x**2, axis=1), numpy pairwise-8 order ---------
__global__ void vq_norms(const float* __restrict__ x, float* __restrict__ A) {
    const int pos = blockIdx.x * 256 + threadIdx.x;
    const int b = pos >> 12, sp = pos & (HW - 1);
    const float* xp = x + (size_t)b * XSTRIDE + sp;
    float xv[D];
#pragma unroll
    for (int d = 0; d < D; ++d) xv[d] = xp[(size_t)d * HW];  // coalesced
    float r[8];
#pragma unroll
    for (int i = 0; i < 8; ++i) r[i] = __fmul_rn(xv[i], xv[i]);
#pragma unroll
    for (int j = 1; j < 8; ++j)
#pragma unroll
        for (int i = 0; i < 8; ++i) r[i] = r[i] + __fmul_rn(xv[8*j+i], xv[8*j+i]);
    A[pos] = ((r[0]+r[1])+(r[2]+r[3])) + ((r[4]+r[5])+(r[6]+r[7]));
}

// ---- main: 512 blocks x 256; block = 128 positions; wave = 2 M-tiles -----
__global__ __launch_bounds__(256, 2)
void vq_main(const float* __restrict__ x, const float* __restrict__ e,
             const unsigned short* __restrict__ ebf,
             const float* __restrict__ c2, const float* __restrict__ A,
             float* __restrict__ out, int* __restrict__ wl_count,
             int* __restrict__ wl) {
    __shared__ int bk_lds[128];
    const int t = threadIdx.x;
    const int lane = t & 63;
    const int w = t >> 6;
    const int p0 = blockIdx.x * 128;
    const int b = p0 >> 12;
    const int sp0 = p0 & (HW - 1);
    const int n = lane & 15;                   // A-row m / B-col n / C col
    const int q = lane >> 4;                   // k-quad / C row group

    // A-frags (registers): xh/xl for 2 M-tiles x 2 K-steps; norms per row
    short8 ah[2][2], al[2][2];
    float An[2][4];
    const int pbase = p0 + w * 32;
#pragma unroll
    for (int mt = 0; mt < 2; ++mt) {
        const int spc = (pbase + mt * 16 + n) & (HW - 1);
#pragma unroll
        for (int s = 0; s < 2; ++s) {
            short8 fh, fl_;
#pragma unroll
            for (int j = 0; j < 8; ++j) {
                const int d = s * 32 + q * 8 + j;      // A[m=n][k=q*8+j]
                const float v = x[(size_t)b * XSTRIDE + (size_t)d * HW + spc];
                const unsigned short h = bf16_rne(v);
                fh[j] = (short)h;
                fl_[j] = (short)bf16_rne(v - bf16_to_f32(h));
            }
            ah[mt][s] = fh; al[mt][s] = fl_;
        }
        const vfloat4 Av = *(const vfloat4*)(A + pbase + mt * 16 + q * 4);
#pragma unroll
        for (int r = 0; r < 4; ++r) An[mt][r] = Av[r];
    }

    const short8* ebv = (const short8*)ebf;
    float s1[2][4], s2[2][4]; int t1[2][4];
#pragma unroll
    for (int mt = 0; mt < 2; ++mt)
#pragma unroll
        for (int r = 0; r < 4; ++r) { s1[mt][r] = 3.4e38f; s2[mt][r] = 3.4e38f; t1[mt][r] = 0; }

    for (int tile = 0; tile < 64; ++tile) {    // no barriers: HW pipelines
        const short8 bh0 = ebv[((tile*2+0)*2+0)*64 + lane];
        const short8 bl0 = ebv[((tile*2+0)*2+1)*64 + lane];
        const short8 bh1 = ebv[((tile*2+1)*2+0)*64 + lane];
        const short8 bl1 = ebv[((tile*2+1)*2+1)*64 + lane];
        const float c2v = c2[tile * 16 + n];
#pragma unroll
        for (int mt = 0; mt < 2; ++mt) {
            vfloat4 acc = {0.f, 0.f, 0.f, 0.f};
            acc = __builtin_amdgcn_mfma_f32_16x16x32_bf16(ah[mt][0], bh0, acc, 0, 0, 0);
            acc = __builtin_amdgcn_mfma_f32_16x16x32_bf16(ah[mt][1], bh1, acc, 0, 0, 0);
            acc = __builtin_amdgcn_mfma_f32_16x16x32_bf16(al[mt][0], bh0, acc, 0, 0, 0);
            acc = __builtin_amdgcn_mfma_f32_16x16x32_bf16(al[mt][1], bh1, acc, 0, 0, 0);
            acc = __builtin_amdgcn_mfma_f32_16x16x32_bf16(ah[mt][0], bl0, acc, 0, 0, 0);
            acc = __builtin_amdgcn_mfma_f32_16x16x32_bf16(ah[mt][1], bl1, acc, 0, 0, 0);
#pragma unroll
            for (int r = 0; r < 4; ++r) {      // C/D: row=q*4+r, col=n
                const float sc = __builtin_fmaf(-2.f, acc[r], An[mt][r]) + c2v;
                const bool lt1 = sc < s1[mt][r];
                const bool lt2 = sc < s2[mt][r];
                s2[mt][r] = lt1 ? s1[mt][r] : (lt2 ? sc : s2[mt][r]);
                s1[mt][r] = lt1 ? sc : s1[mt][r];
                t1[mt][r] = lt1 ? tile : t1[mt][r];
            }
        }
    }

    // merge top-2 across the 16 code-columns (lanes within a q-group)
#pragma unroll
    for (int mt = 0; mt < 2; ++mt)
#pragma unroll
        for (int r = 0; r < 4; ++r) {
            float a1 = s1[mt][r], a2 = s2[mt][r];
            int ak = t1[mt][r] * 16 + n;
#pragma unroll
            for (int m = 1; m < 16; m <<= 1) {
                const float o1 = __shfl_xor(a1, m, 64);
                const float o2 = __shfl_xor(a2, m, 64);
                const int   ok = __shfl_xor(ak, m, 64);
                const bool take = (o1 < a1) || (o1 == a1 && ok < ak);
                const float loser = take ? a1 : o1;
                a1 = take ? o1 : a1;
                ak = take ? ok : ak;
                a2 = fminf(fminf(a2, o2), loser);
            }
            if (n == 0) {
                const int pl = w * 32 + mt * 16 + q * 4 + r;
                bk_lds[pl] = ak;
                if (a2 - a1 <= MARGIN) {       // not certified -> exact redo
                    const int idx = atomicAdd(wl_count, 1);
                    wl[idx] = p0 + pl;
                }
            }
        }
    __syncthreads();

    // write all 128 positions x 64 channels (fallback overwrites ambiguous)
    const int pl = t & 127;
    const int half = t >> 7;
    const int bk = bk_lds[pl];
    const int sp = sp0 + pl;
    const float* xb = x + (size_t)b * XSTRIDE + sp;
    float* ob = out + (size_t)b * XSTRIDE + sp;
#pragma unroll
    for (int i = 0; i < 32; ++i) {
        const int c = half * 32 + i;
        const float xq = xb[(size_t)c * HW];
        const float qv = e[c * K + bk];
        ob[(size_t)c * HW] = xq + (qv - xq);   // np STE: fl(x + fl(q-x))
    }
}

// ---- fallback: bit-exact np scan for ambiguous positions -----------------
__global__ __launch_bounds__(256, 2)
void vq_fallback(const float* __restrict__ x, const float* __restrict__ e,
                 const float* __restrict__ c2, const float* __restrict__ A,
                 const int* __restrict__ wl_count, const int* __restrict__ wl,
                 float* __restrict__ out) {
    __shared__ float rs[256];
    __shared__ int   rk[256];
    const int t = threadIdx.x;
    const int count = *wl_count;
    for (int i = blockIdx.x; i < count; i += gridDim.x) {
        const int pos = wl[i];
        const int b = pos >> 12, sp = pos & (HW - 1);
        const float Ap = A[pos];
        float bs = 3.4e38f; int bk = 0x7fffffff;
#pragma unroll
        for (int j = 0; j < 4; ++j) {
            const int k = t + 256 * j;         // ascending k per thread
            float acc = 0.f;
            for (int d = 0; d < D; ++d)        // sequential-k FMA chain (np)
                acc = __builtin_fmaf(x[(size_t)b * XSTRIDE + (size_t)d * HW + sp],
                                     e[d * K + k], acc);
            const float sc = __builtin_fmaf(-2.f, acc, Ap) + c2[k];
            if (sc < bs || (sc == bs && k < bk)) { bs = sc; bk = k; }
        }
        rs[t] = bs; rk[t] = bk;
        __syncthreads();
        for (int off = 128; off > 0; off >>= 1) {
            if (t < off) {
                const float so = rs[t + off]; const int ko = rk[t + off];
                if (so < rs[t] || (so == rs[t] && ko < rk[t])) { rs[t] = so; rk[t] = ko; }
            }
            __syncthreads();
        }
        const int kb = rk[0];
        if (t < 64) {
            const float xq = x[(size_t)b * XSTRIDE + (size_t)t * HW + sp];
            const float qv = e[t * K + kb];
            out[(size_t)b * XSTRIDE + (size_t)t * HW + sp] = xq + (qv - xq);
        }
        __syncthreads();
    }
}

extern "C" void kernel_launch(void* const* d_in, const int* in_sizes, int n_in,
                              void* d_out, int out_size, void* d_ws, size_t ws_size,
                              hipStream_t stream) {
    const float* x = (const float*)d_in[0];
    const float* e = (const float*)d_in[1];
    float* out = (float*)d_out;

    char* ws = (char*)d_ws;                          // ~790 KB used
    unsigned short* ebf = (unsigned short*)ws;       // 256 KB B-fragments
    float* c2 = (float*)(ws + 262144);               // 4 KB
    float* A  = (float*)(ws + 266240);               // 256 KB norms
    int* wl_count = (int*)(ws + 528384);             // 16 B
    int* wl = (int*)(ws + 528400);                   // 256 KB worklist

    vq_prep_e<<<64, 256, 0, stream>>>(e, ebf);
    vq_prep_c2<<<4, 256, 0, stream>>>(e, c2, wl_count);
    vq_norms<<<NPOS / 256, 256, 0, stream>>>(x, A);
    vq_main<<<NPOS / 128, 256, 0, stream>>>(x, e, ebf, c2, A, out, wl_count, wl);
    vq_fallback<<<256, 256, 0, stream>>>(x, e, c2, A, wl_count, wl, out);
}